// Round 1
// baseline (7849.615 us; speedup 1.0000x reference)
//
#include <hip/hip_runtime.h>

#define SEQL 1024
#define BATCHN 128
#define UNITS 256
#define INDIM 128
#define G3 768   // r|u|h gate columns

typedef __attribute__((ext_vector_type(8))) short short8;
typedef __attribute__((ext_vector_type(4))) float floatx4;

__device__ __forceinline__ short f2bf(float f) {
  unsigned u = __float_as_uint(f);
  u += 0x7fff + ((u >> 16) & 1);   // round-to-nearest-even
  return (short)(u >> 16);
}
__device__ __forceinline__ float bf2f(unsigned short s) {
  return __uint_as_float(((unsigned)s) << 16);
}

// ---------------------------------------------------------------------------
// Kernel A: build combined input weight WcB (384x768 bf16, MFMA-frag layout)
// and recurrent weight WhB (256x768 bf16, frag layout).
// Frag layout: element W[k][n] stored at ((n*KKmax + kk)*4 + q)*8 + j,
// kk=k>>5, q=(k>>3)&3, j=k&7 -> lane L of a wave loads 16B contiguous.
// ---------------------------------------------------------------------------
__global__ void prep_kernel(const float* __restrict__ iw,   // (128,1792)
                            const float* __restrict__ hw,   // (256,768)
                            short* __restrict__ WcB, short* __restrict__ WhB) {
  int idx = blockIdx.x * 256 + threadIdx.x;
  const int WCN = 384 * G3;
  if (idx < WCN) {
    int k = idx / G3, n = idx % G3;
    int i = k & 127, blkk = k >> 7;      // 0:x_t 1:x_{t-1} 2:x_{t-2}
    int gsel = n >> 8, c = n & 255;      // 0:r 1:u 2:h
    const float* row = iw + (size_t)i * 1792;
    float v;
    if (blkk == 0) {
      v = (gsel == 0) ? row[c] + row[768 + c] + row[1280 + c]
        : (gsel == 1) ? row[256 + c] + row[1024 + c] + row[1536 + c]
                      : row[512 + c];
    } else if (blkk == 1) {
      v = (gsel == 0) ? -(row[768 + c] + 2.f * row[1280 + c])
        : (gsel == 1) ? -(row[1024 + c] + 2.f * row[1536 + c])
                      : 0.f;
    } else {
      v = (gsel == 0) ? row[1280 + c]
        : (gsel == 1) ? row[1536 + c]
                      : 0.f;
    }
    int kk = k >> 5, q = (k >> 3) & 3, j = k & 7;
    WcB[(((n * 12 + kk) * 4 + q) * 8) + j] = f2bf(v);
  } else {
    idx -= WCN;
    if (idx < 256 * G3) {
      int k = idx / G3, n = idx % G3;
      float v = hw[(size_t)k * G3 + n];
      int kk = k >> 5, q = (k >> 3) & 3, j = k & 7;
      WhB[(((n * 8 + kk) * 4 + q) * 8) + j] = f2bf(v);
    }
  }
}

// ---------------------------------------------------------------------------
// Kernel B: input projection. pre[bt][c] (bf16) = Xcat[bt] @ Wc + bias.
// One wave computes a 16(bt) x 64(col) tile via 12 K-blocks of 16x16x32 MFMA.
// ---------------------------------------------------------------------------
__global__ __launch_bounds__(256) void proj_kernel(const float* __restrict__ x,
                                                   const short* __restrict__ WcB,
                                                   const float* __restrict__ bias,
                                                   short* __restrict__ pre) {
  const int tid = threadIdx.x;
  const int lane = tid & 63, ln16 = lane & 15, q = lane >> 4;
  const int gw = blockIdx.x * 4 + (tid >> 6);
  const int ngrp = gw % 12;          // 64-col group
  const int mt = gw / 12;            // 16-row group of bt
  const int bt0 = mt * 16;
  const int b = bt0 >> 10;           // SEQ = 1024
  const int t0 = bt0 & 1023;
  const int t = t0 + ln16;           // A-operand row (m = lane&15)
  const float* xb = x + (size_t)b * SEQL * INDIM;

  short8 afr[12];
#pragma unroll
  for (int kk = 0; kk < 12; ++kk) {
    int dt = kk >> 2;
    int kin = (kk & 3) * 32 + q * 8;
    short8 af;
    if (t >= dt) {
      const float* p = xb + (size_t)(t - dt) * INDIM + kin;
      floatx4 a0 = *(const floatx4*)p;
      floatx4 a1 = *(const floatx4*)(p + 4);
#pragma unroll
      for (int j = 0; j < 4; ++j) { af[j] = f2bf(a0[j]); af[4 + j] = f2bf(a1[j]); }
    } else {
#pragma unroll
      for (int j = 0; j < 8; ++j) af[j] = 0;
    }
    afr[kk] = af;
  }

  floatx4 acc[4];
#pragma unroll
  for (int nt = 0; nt < 4; ++nt) {
    float bv = bias[ngrp * 64 + nt * 16 + ln16];
#pragma unroll
    for (int r = 0; r < 4; ++r) acc[nt][r] = bv;
  }
#pragma unroll
  for (int kk = 0; kk < 12; ++kk) {
#pragma unroll
    for (int nt = 0; nt < 4; ++nt) {
      int n = ngrp * 64 + nt * 16 + ln16;
      short8 w = *(const short8*)(WcB + (((size_t)(n * 12 + kk) * 4 + q) * 8));
      acc[nt] = __builtin_amdgcn_mfma_f32_16x16x32_bf16(afr[kk], w, acc[nt], 0, 0, 0);
    }
  }
#pragma unroll
  for (int nt = 0; nt < 4; ++nt) {
    int col = ngrp * 64 + nt * 16 + ln16;
#pragma unroll
    for (int r = 0; r < 4; ++r) {
      int row = q * 4 + r;                         // C row = (lane>>4)*4 + reg
      pre[(size_t)(bt0 + row) * G3 + col] = f2bf(acc[nt][r]);
    }
  }
}

// ---------------------------------------------------------------------------
// Kernel C: persistent recurrence. 8 workgroups x 512 threads (8 waves),
// each handles 16 batch rows for all 1024 steps. Recurrent weights live in
// registers (192 VGPR/wave). h kept f32 in LDS; bf16 copies feed MFMA.
// ---------------------------------------------------------------------------
__global__ __launch_bounds__(512, 2) void rnn_kernel(const short* __restrict__ pre,
                                                     const short* __restrict__ WhB,
                                                     float* __restrict__ out) {
  __shared__ __align__(16) float hS[16][UNITS + 8];
  __shared__ __align__(16) float uS[16][UNITS + 8];
  __shared__ __align__(16) short hB[16][UNITS + 8];
  __shared__ __align__(16) short rhB[16][UNITS + 8];

  const int tid = threadIdx.x;
  const int wave = tid >> 6;
  const int lane = tid & 63, ln16 = lane & 15, q = lane >> 4;
  const int b0 = blockIdx.x * 16;

  // persistent weight fragments
  short8 wA[4][8];   // phase A: cols wave*64 .. wave*64+63 of [Whr|Whu]
#pragma unroll
  for (int nt = 0; nt < 4; ++nt) {
    int n = wave * 64 + nt * 16 + ln16;
#pragma unroll
    for (int kk = 0; kk < 8; ++kk)
      wA[nt][kk] = *(const short8*)(WhB + (((size_t)(n * 8 + kk) * 4 + q) * 8));
  }
  short8 wB[2][8];   // phase B: cols wave*32 .. +31 of Whh (n = 512+col)
#pragma unroll
  for (int nt = 0; nt < 2; ++nt) {
    int n = 512 + wave * 32 + nt * 16 + ln16;
#pragma unroll
    for (int kk = 0; kk < 8; ++kk)
      wB[nt][kk] = *(const short8*)(WhB + (((size_t)(n * 8 + kk) * 4 + q) * 8));
  }

  for (int i = tid; i < 16 * (UNITS + 8); i += 512) {
    int r = i / (UNITS + 8), c = i % (UNITS + 8);
    hS[r][c] = 0.f; uS[r][c] = 0.f; hB[r][c] = 0; rhB[r][c] = 0;
  }
  __syncthreads();

  const short* preB = pre + (size_t)b0 * SEQL * G3;
  float* outB = out + (size_t)b0 * SEQL * UNITS;

  for (int t = 0; t < SEQL; ++t) {
    // issue ALL pre loads (both phases) up front so phase-B values arrive
    // during phase-A compute
    floatx4 acc[4];
#pragma unroll
    for (int nt = 0; nt < 4; ++nt) {
      const int col = wave * 64 + nt * 16 + ln16;
#pragma unroll
      for (int r = 0; r < 4; ++r) {
        const int row = q * 4 + r;
        acc[nt][r] = bf2f((unsigned short)preB[((size_t)row * SEQL + t) * G3 + col]);
      }
    }
    floatx4 acc2[2];
#pragma unroll
    for (int nt = 0; nt < 2; ++nt) {
      const int col = wave * 32 + nt * 16 + ln16;
#pragma unroll
      for (int r = 0; r < 4; ++r) {
        const int row = q * 4 + r;
        acc2[nt][r] = bf2f((unsigned short)preB[((size_t)row * SEQL + t) * G3 + 512 + col]);
      }
    }

    // Phase A: r,u pre-activations (cols 0..511)
#pragma unroll
    for (int kk = 0; kk < 8; ++kk) {
      const short8 a = *(const short8*)&hB[ln16][kk * 32 + q * 8];
      acc[0] = __builtin_amdgcn_mfma_f32_16x16x32_bf16(a, wA[0][kk], acc[0], 0, 0, 0);
      acc[1] = __builtin_amdgcn_mfma_f32_16x16x32_bf16(a, wA[1][kk], acc[1], 0, 0, 0);
      acc[2] = __builtin_amdgcn_mfma_f32_16x16x32_bf16(a, wA[2][kk], acc[2], 0, 0, 0);
      acc[3] = __builtin_amdgcn_mfma_f32_16x16x32_bf16(a, wA[3][kk], acc[3], 0, 0, 0);
    }
    if (wave < 4) {          // r gates -> rhB = bf16(sigmoid * h)
#pragma unroll
      for (int nt = 0; nt < 4; ++nt) {
        const int col = wave * 64 + nt * 16 + ln16;
#pragma unroll
        for (int r = 0; r < 4; ++r) {
          const int row = q * 4 + r;
          float s = 1.f / (1.f + __expf(-acc[nt][r]));
          rhB[row][col] = f2bf(s * hS[row][col]);
        }
      }
    } else {                 // u gates -> uS
#pragma unroll
      for (int nt = 0; nt < 4; ++nt) {
        const int col = (wave - 4) * 64 + nt * 16 + ln16;
#pragma unroll
        for (int r = 0; r < 4; ++r) {
          const int row = q * 4 + r;
          uS[row][col] = 1.f / (1.f + __expf(-acc[nt][r]));
        }
      }
    }
    __syncthreads();

    // Phase B: cand = tanh(preH + (r*h)@Whh); h update
#pragma unroll
    for (int kk = 0; kk < 8; ++kk) {
      const short8 a = *(const short8*)&rhB[ln16][kk * 32 + q * 8];
      acc2[0] = __builtin_amdgcn_mfma_f32_16x16x32_bf16(a, wB[0][kk], acc2[0], 0, 0, 0);
      acc2[1] = __builtin_amdgcn_mfma_f32_16x16x32_bf16(a, wB[1][kk], acc2[1], 0, 0, 0);
    }
#pragma unroll
    for (int nt = 0; nt < 2; ++nt) {
      const int col = wave * 32 + nt * 16 + ln16;
#pragma unroll
      for (int r = 0; r < 4; ++r) {
        const int row = q * 4 + r;
        float e = __expf(2.f * acc2[nt][r]);
        float cand = 1.f - 2.f / (e + 1.f);       // tanh, saturates cleanly
        float ug = uS[row][col];
        float hold = hS[row][col];
        float hnew = ug * hold + (1.f - ug) * cand;
        hS[row][col] = hnew;
        hB[row][col] = f2bf(hnew);
        outB[((size_t)row * SEQL + t) * UNITS + col] = hnew;
      }
    }
    __syncthreads();
  }
}

extern "C" void kernel_launch(void* const* d_in, const int* in_sizes, int n_in,
                              void* d_out, int out_size, void* d_ws, size_t ws_size,
                              hipStream_t stream) {
  const float* x    = (const float*)d_in[0];
  const float* iw   = (const float*)d_in[1];
  const float* hw   = (const float*)d_in[2];
  const float* bias = (const float*)d_in[3];
  // d_in[4] (constant) is [I;0] — folded analytically, unused.
  float* out = (float*)d_out;

  short* pre = (short*)d_ws;                           // 131072*768 bf16 = 192 MB
  const size_t preElems = (size_t)BATCHN * SEQL * G3;
  short* WcB = pre + preElems;                         // 384*768 bf16
  short* WhB = WcB + (size_t)384 * G3;                 // 256*768 bf16

  prep_kernel<<<1920, 256, 0, stream>>>(iw, hw, WcB, WhB);
  proj_kernel<<<24576, 256, 0, stream>>>(x, WcB, bias, pre);
  rnn_kernel<<<8, 512, 0, stream>>>(pre, WhB, out);
}

// Round 2
// 2506.766 us; speedup vs baseline: 3.1314x; 3.1314x over previous
//
#include <hip/hip_runtime.h>

#define SEQL 1024
#define BATCHN 128
#define UNITS 256
#define INDIM 128
#define G3 768   // r|u|h gate columns

typedef __attribute__((ext_vector_type(8))) short short8;
typedef __attribute__((ext_vector_type(4))) short short4v;
typedef __attribute__((ext_vector_type(4))) float floatx4;

#define NL2E  -1.4426950408889634f   // -log2(e): r,u gate scale
#define PL2E2  2.8853900817779268f   //  2*log2(e): h gate scale

__device__ __forceinline__ short f2bf(float f) {
  unsigned u = __float_as_uint(f);
  u += 0x7fff + ((u >> 16) & 1);   // round-to-nearest-even
  return (short)(u >> 16);
}
__device__ __forceinline__ float bf2f(unsigned short s) {
  return __uint_as_float(((unsigned)s) << 16);
}
__device__ __forceinline__ float fexp2(float x) {
#if __has_builtin(__builtin_amdgcn_exp2f)
  return __builtin_amdgcn_exp2f(x);
#else
  return __expf(0.6931471805599453f * x);
#endif
}
__device__ __forceinline__ float frcp(float x) {
#if __has_builtin(__builtin_amdgcn_rcpf)
  return __builtin_amdgcn_rcpf(x);
#else
  return 1.f / x;
#endif
}

// ---------------------------------------------------------------------------
// Kernel A: combined input weight WcB (384x768 bf16, B-frag layout) and
// recurrent weight WhB (256x768 bf16, B-frag layout), gate-scaled so the
// epilogues are pure exp2/rcp:  r,u cols x(-log2e);  h cols x(+2 log2e).
// Frag layout: W[k][n] at ((n*KKmax + kk)*4 + q)*8 + j, kk=k>>5,q=(k>>3)&3,j=k&7.
// ---------------------------------------------------------------------------
__global__ void prep_kernel(const float* __restrict__ iw,   // (128,1792)
                            const float* __restrict__ hw,   // (256,768)
                            short* __restrict__ WcB, short* __restrict__ WhB) {
  int idx = blockIdx.x * 256 + threadIdx.x;
  const int WCN = 384 * G3;
  if (idx < WCN) {
    int k = idx / G3, n = idx % G3;
    int i = k & 127, blkk = k >> 7;      // 0:x_t 1:x_{t-1} 2:x_{t-2}
    int gsel = n >> 8, c = n & 255;      // 0:r 1:u 2:h
    const float* row = iw + (size_t)i * 1792;
    float v;
    if (blkk == 0) {
      v = (gsel == 0) ? row[c] + row[768 + c] + row[1280 + c]
        : (gsel == 1) ? row[256 + c] + row[1024 + c] + row[1536 + c]
                      : row[512 + c];
    } else if (blkk == 1) {
      v = (gsel == 0) ? -(row[768 + c] + 2.f * row[1280 + c])
        : (gsel == 1) ? -(row[1024 + c] + 2.f * row[1536 + c])
                      : 0.f;
    } else {
      v = (gsel == 0) ? row[1280 + c]
        : (gsel == 1) ? row[1536 + c]
                      : 0.f;
    }
    v *= (gsel == 2) ? PL2E2 : NL2E;
    int kk = k >> 5, q = (k >> 3) & 3, j = k & 7;
    WcB[(((n * 12 + kk) * 4 + q) * 8) + j] = f2bf(v);
  } else {
    idx -= WCN;
    if (idx < 256 * G3) {
      int k = idx / G3, n = idx % G3;
      float v = hw[(size_t)k * G3 + n] * ((n >> 8) == 2 ? PL2E2 : NL2E);
      int kk = k >> 5, q = (k >> 3) & 3, j = k & 7;
      WhB[(((n * 8 + kk) * 4 + q) * 8) + j] = f2bf(v);
    }
  }
}

// ---------------------------------------------------------------------------
// Kernel B: input projection, tiled M=16 BATCH rows (not time!), so the MFMA
// C-fragment maps 1:1 onto the rnn kernel's thread layout. Output stored as
// per-(wg,t) contiguous 24.5KB slabs: 3 chunks (r|u|h) x 512 "rnn-tid" x 8 bf16.
// x is staged via LDS directly into A-fragment order (coalesced row loads).
// ---------------------------------------------------------------------------
__global__ __launch_bounds__(256) void proj_kernel(const float* __restrict__ x,
                                                   const short* __restrict__ WcB,
                                                   const float* __restrict__ bias,
                                                   short* __restrict__ pre2) {
  __shared__ short xF[12 * 64 * 8];     // A-frag: [kk][lane][8] bf16, 12KB
  const int tid = threadIdx.x;
  const int t = blockIdx.x >> 3;
  const int wgb = blockIdx.x & 7;

#pragma unroll
  for (int it = 0; it < 6; ++it) {
    int rr = it * 8 + (tid >> 5);       // 0..47 = dt*16 + bb
    int dt = rr >> 4, bb = rr & 15;
    int lane32 = tid & 31, c = lane32 * 4;
    floatx4 v = {0.f, 0.f, 0.f, 0.f};
    if (t >= dt)
      v = *(const floatx4*)(x + ((size_t)(wgb * 16 + bb) * SEQL + (t - dt)) * INDIM + c);
    int kk = dt * 4 + (c >> 5), qq = (c >> 3) & 3, j0 = c & 7;
    short4v pk;
#pragma unroll
    for (int j = 0; j < 4; ++j) pk[j] = f2bf(v[j]);
    *(short4v*)&xF[((kk * 64 + qq * 16 + bb) * 8) + j0] = pk;
  }
  __syncthreads();

  const int wv = tid >> 6, lane = tid & 63, ln16 = lane & 15;
  const int q = lane >> 4;

  short8 aF[12];
#pragma unroll
  for (int kk = 0; kk < 12; ++kk) aF[kk] = *(const short8*)&xF[(kk * 64 + lane) * 8];

  short* slab = pre2 + (size_t)(wgb * SEQL + t) * 3 * 4096;   // 3 chunks x 4096 shorts

#pragma unroll
  for (int ig = 0; ig < 3; ++ig) {
    const int ngrp = wv * 3 + ig;                  // 0..11 -> 64-col group
    const float sc = (ngrp >= 8) ? PL2E2 : NL2E;
    floatx4 acc[4];
#pragma unroll
    for (int nt = 0; nt < 4; ++nt) {
      float bv = bias[ngrp * 64 + nt * 16 + ln16] * sc;
#pragma unroll
      for (int r = 0; r < 4; ++r) acc[nt][r] = bv;
    }
#pragma unroll
    for (int kk = 0; kk < 12; ++kk) {
#pragma unroll
      for (int nt = 0; nt < 4; ++nt) {
        int n = ngrp * 64 + nt * 16 + ln16;
        short8 w = *(const short8*)(WcB + (((size_t)(n * 12 + kk) * 4 + q) * 8));
        acc[nt] = __builtin_amdgcn_mfma_f32_16x16x32_bf16(aF[kk], w, acc[nt], 0, 0, 0);
      }
    }
    const int g = ngrp >> 2;                       // chunk 0:r 1:u 2:h
#pragma unroll
    for (int nt = 0; nt < 4; ++nt) {
      int wave_r = (ngrp & 3) * 2 + (nt >> 1);
      int tid_r = wave_r * 64 + lane;
      short4v pk;
#pragma unroll
      for (int r = 0; r < 4; ++r) pk[r] = f2bf(acc[nt][r]);
      *(short4v*)(slab + g * 4096 + tid_r * 8 + (nt & 1) * 4) = pk;
    }
  }
}

// ---------------------------------------------------------------------------
// Kernel C: persistent recurrence. 8 WGs x 512 threads; 16 batch rows per WG.
// Per step/thread: 3 coalesced dwordx4 pre loads (prefetched 1 step ahead),
// phase A (r,u: 32 MFMA), phase B (cand: 16 MFMA). h and u live in registers;
// only bf16 A-fragments hF/rF round-trip through LDS.
// ---------------------------------------------------------------------------
__global__ __launch_bounds__(512, 2) void rnn_kernel(const short* __restrict__ pre2,
                                                     const short* __restrict__ WhB,
                                                     float* __restrict__ out) {
  __shared__ short hF[8 * 64 * 8];      // h   A-frag, [kk][lane][8], 8KB
  __shared__ short rF[8 * 64 * 8];      // r*h A-frag, 8KB

  const int tid = threadIdx.x;
  const int wv = tid >> 6, lane = tid & 63, ln16 = lane & 15, q = lane >> 4;
  const int wg = blockIdx.x;

  // persistent weight fragments: this wave's 32 cols of each gate
  short8 wR[2][8], wU[2][8], wH[2][8];
#pragma unroll
  for (int nt = 0; nt < 2; ++nt) {
    int nr = wv * 32 + nt * 16 + ln16;
#pragma unroll
    for (int kk = 0; kk < 8; ++kk) {
      wR[nt][kk] = *(const short8*)(WhB + (((size_t)(nr * 8 + kk) * 4 + q) * 8));
      wU[nt][kk] = *(const short8*)(WhB + (((size_t)((256 + nr) * 8 + kk) * 4 + q) * 8));
      wH[nt][kk] = *(const short8*)(WhB + (((size_t)((512 + nr) * 8 + kk) * 4 + q) * 8));
    }
  }
  for (int i = tid; i < 8 * 64 * 8; i += 512) { hF[i] = 0; rF[i] = 0; }

  float hreg[2][4] = {{0.f, 0.f, 0.f, 0.f}, {0.f, 0.f, 0.f, 0.f}};

  const short* slab0 = pre2 + (size_t)wg * SEQL * 3 * 4096;
  short8 cur0 = *(const short8*)(slab0 + 0 * 4096 + tid * 8);
  short8 cur1 = *(const short8*)(slab0 + 1 * 4096 + tid * 8);
  short8 cur2 = *(const short8*)(slab0 + 2 * 4096 + tid * 8);

  // frag write address for this thread's (nt,r) elements (row=q*4+r, col=wv*32+nt*16+ln16)
  const int fwbase = (wv * 64 + (ln16 >> 3) * 16 + q * 4) * 8 + (ln16 & 7);
  float* outBase = out + (size_t)(wg * 16 + q * 4) * SEQL * UNITS + wv * 32 + ln16;

  __syncthreads();

  for (int t = 0; t < SEQL; ++t) {
    const short* nslab = slab0 + (size_t)(t < SEQL - 1 ? t + 1 : t) * 3 * 4096;
    short8 nxt0 = *(const short8*)(nslab + 0 * 4096 + tid * 8);
    short8 nxt1 = *(const short8*)(nslab + 1 * 4096 + tid * 8);
    short8 nxt2 = *(const short8*)(nslab + 2 * 4096 + tid * 8);

    // ---- phase A: r,u pre-acts for cols wv*32 .. +31 ----
    floatx4 accR[2], accU[2];
#pragma unroll
    for (int nt = 0; nt < 2; ++nt)
#pragma unroll
      for (int r = 0; r < 4; ++r) {
        accR[nt][r] = bf2f((unsigned short)cur0[nt * 4 + r]);
        accU[nt][r] = bf2f((unsigned short)cur1[nt * 4 + r]);
      }
#pragma unroll
    for (int kk = 0; kk < 8; ++kk) {
      const short8 a = *(const short8*)&hF[(kk * 64 + lane) * 8];
      accR[0] = __builtin_amdgcn_mfma_f32_16x16x32_bf16(a, wR[0][kk], accR[0], 0, 0, 0);
      accR[1] = __builtin_amdgcn_mfma_f32_16x16x32_bf16(a, wR[1][kk], accR[1], 0, 0, 0);
      accU[0] = __builtin_amdgcn_mfma_f32_16x16x32_bf16(a, wU[0][kk], accU[0], 0, 0, 0);
      accU[1] = __builtin_amdgcn_mfma_f32_16x16x32_bf16(a, wU[1][kk], accU[1], 0, 0, 0);
    }
    float ureg[2][4];
#pragma unroll
    for (int nt = 0; nt < 2; ++nt)
#pragma unroll
      for (int r = 0; r < 4; ++r) {
        float rg = frcp(1.f + fexp2(accR[nt][r]));        // sigmoid (scale folded)
        ureg[nt][r] = frcp(1.f + fexp2(accU[nt][r]));
        rF[fwbase + (nt * 32 + r) * 8] = f2bf(rg * hreg[nt][r]);
      }
    __syncthreads();

    // ---- phase B: cand for cols wv*32 .. +31; h update ----
    floatx4 accH[2];
#pragma unroll
    for (int nt = 0; nt < 2; ++nt)
#pragma unroll
      for (int r = 0; r < 4; ++r) accH[nt][r] = bf2f((unsigned short)cur2[nt * 4 + r]);
#pragma unroll
    for (int kk = 0; kk < 8; ++kk) {
      const short8 a = *(const short8*)&rF[(kk * 64 + lane) * 8];
      accH[0] = __builtin_amdgcn_mfma_f32_16x16x32_bf16(a, wH[0][kk], accH[0], 0, 0, 0);
      accH[1] = __builtin_amdgcn_mfma_f32_16x16x32_bf16(a, wH[1][kk], accH[1], 0, 0, 0);
    }
#pragma unroll
    for (int nt = 0; nt < 2; ++nt)
#pragma unroll
      for (int r = 0; r < 4; ++r) {
        float cand = 1.f - 2.f * frcp(1.f + fexp2(accH[nt][r]));   // tanh (scale folded)
        float u = ureg[nt][r];
        float hnew = u * (hreg[nt][r] - cand) + cand;
        hreg[nt][r] = hnew;
        hF[fwbase + (nt * 32 + r) * 8] = f2bf(hnew);
        outBase[(size_t)r * (SEQL * UNITS) + (size_t)t * UNITS + nt * 16] = hnew;
      }
    cur0 = nxt0; cur1 = nxt1; cur2 = nxt2;
    __syncthreads();
  }
}

extern "C" void kernel_launch(void* const* d_in, const int* in_sizes, int n_in,
                              void* d_out, int out_size, void* d_ws, size_t ws_size,
                              hipStream_t stream) {
  const float* x    = (const float*)d_in[0];
  const float* iw   = (const float*)d_in[1];
  const float* hw   = (const float*)d_in[2];
  const float* bias = (const float*)d_in[3];
  // d_in[4] (constant) is [I;0] — folded analytically, unused.
  float* out = (float*)d_out;

  short* pre2 = (short*)d_ws;                          // 8*1024*3*4096 shorts = 192 MB
  const size_t preElems = (size_t)8 * SEQL * 3 * 4096;
  short* WcB = pre2 + preElems;                        // 384*768 bf16
  short* WhB = WcB + (size_t)384 * G3;                 // 256*768 bf16

  prep_kernel<<<1920, 256, 0, stream>>>(iw, hw, WcB, WhB);
  proj_kernel<<<8192, 256, 0, stream>>>(x, WcB, bias, pre2);
  rnn_kernel<<<8, 512, 0, stream>>>(pre2, WhB, out);
}

// Round 3
// 1839.364 us; speedup vs baseline: 4.2676x; 1.3628x over previous
//
#include <hip/hip_runtime.h>

#define SEQL 1024
#define BATCHN 128
#define UNITS 256
#define INDIM 128
#define G3 768   // r|u|h gate columns

typedef __attribute__((ext_vector_type(8))) short short8;
typedef __attribute__((ext_vector_type(4))) short short4v;
typedef __attribute__((ext_vector_type(4))) float floatx4;

#define NL2E  -1.4426950408889634f   // -log2(e): r,u gate scale
#define PL2E2  2.8853900817779268f   //  2*log2(e): h gate scale

#define HSTRIDE 272                  // compact h row stride (shorts), breaks bank alias

__device__ __forceinline__ short f2bf(float f) {
  unsigned u = __float_as_uint(f);
  u += 0x7fff + ((u >> 16) & 1);   // round-to-nearest-even
  return (short)(u >> 16);
}
__device__ __forceinline__ float bf2f(unsigned short s) {
  return __uint_as_float(((unsigned)s) << 16);
}
__device__ __forceinline__ float fexp2(float x) {
#if __has_builtin(__builtin_amdgcn_exp2f)
  return __builtin_amdgcn_exp2f(x);
#else
  return __expf(0.6931471805599453f * x);
#endif
}
__device__ __forceinline__ float frcp(float x) {
#if __has_builtin(__builtin_amdgcn_rcpf)
  return __builtin_amdgcn_rcpf(x);
#else
  return 1.f / x;
#endif
}

// ---------------------------------------------------------------------------
// Kernel A: combined input weight WcB (384x768 bf16, B-frag layout) and
// recurrent weight WhB (256x768 bf16, B-frag layout), gate-scaled so the
// epilogues are pure exp2/rcp:  r,u cols x(-log2e);  h cols x(+2 log2e).
// Frag layout: W[k][n] at ((n*KKmax + kk)*4 + q)*8 + j, kk=k>>5,q=(k>>3)&3,j=k&7.
// ---------------------------------------------------------------------------
__global__ void prep_kernel(const float* __restrict__ iw,   // (128,1792)
                            const float* __restrict__ hw,   // (256,768)
                            short* __restrict__ WcB, short* __restrict__ WhB) {
  int idx = blockIdx.x * 256 + threadIdx.x;
  const int WCN = 384 * G3;
  if (idx < WCN) {
    int k = idx / G3, n = idx % G3;
    int i = k & 127, blkk = k >> 7;      // 0:x_t 1:x_{t-1} 2:x_{t-2}
    int gsel = n >> 8, c = n & 255;      // 0:r 1:u 2:h
    const float* row = iw + (size_t)i * 1792;
    float v;
    if (blkk == 0) {
      v = (gsel == 0) ? row[c] + row[768 + c] + row[1280 + c]
        : (gsel == 1) ? row[256 + c] + row[1024 + c] + row[1536 + c]
                      : row[512 + c];
    } else if (blkk == 1) {
      v = (gsel == 0) ? -(row[768 + c] + 2.f * row[1280 + c])
        : (gsel == 1) ? -(row[1024 + c] + 2.f * row[1536 + c])
                      : 0.f;
    } else {
      v = (gsel == 0) ? row[1280 + c]
        : (gsel == 1) ? row[1536 + c]
                      : 0.f;
    }
    v *= (gsel == 2) ? PL2E2 : NL2E;
    int kk = k >> 5, q = (k >> 3) & 3, j = k & 7;
    WcB[(((n * 12 + kk) * 4 + q) * 8) + j] = f2bf(v);
  } else {
    idx -= WCN;
    if (idx < 256 * G3) {
      int k = idx / G3, n = idx % G3;
      float v = hw[(size_t)k * G3 + n] * ((n >> 8) == 2 ? PL2E2 : NL2E);
      int kk = k >> 5, q = (k >> 3) & 3, j = k & 7;
      WhB[(((n * 8 + kk) * 4 + q) * 8) + j] = f2bf(v);
    }
  }
}

// ---------------------------------------------------------------------------
// Kernel B: input projection (M=16 batch rows per block). Output stored as
// per-(rnn_wg, t) slabs of 3x512 dwords: slab[g*512 + tid] = pack(nt0, nt1)
// where tid = wv*64 + q*16 + ln16 is the CONSUMING rnn thread; rnn_wg owns
// 4 batch rows (wg = mt*4 + q_proj, row-in-wg = reg r).
// ---------------------------------------------------------------------------
__global__ __launch_bounds__(256) void proj_kernel(const float* __restrict__ x,
                                                   const short* __restrict__ WcB,
                                                   const float* __restrict__ bias,
                                                   unsigned* __restrict__ pre2) {
  __shared__ short xF[12 * 64 * 8];     // A-frag: [kk][lane][8] bf16, 12KB
  const int tid = threadIdx.x;
  const int t = blockIdx.x >> 3;
  const int mt = blockIdx.x & 7;        // 16-row batch group

#pragma unroll
  for (int it = 0; it < 6; ++it) {
    int rr = it * 8 + (tid >> 5);       // 0..47 = dt*16 + bb
    int dt = rr >> 4, bb = rr & 15;
    int lane32 = tid & 31, c = lane32 * 4;
    floatx4 v = {0.f, 0.f, 0.f, 0.f};
    if (t >= dt)
      v = *(const floatx4*)(x + ((size_t)(mt * 16 + bb) * SEQL + (t - dt)) * INDIM + c);
    int kk = dt * 4 + (c >> 5), qq = (c >> 3) & 3, j0 = c & 7;
    short4v pk;
#pragma unroll
    for (int j = 0; j < 4; ++j) pk[j] = f2bf(v[j]);
    *(short4v*)&xF[((kk * 64 + qq * 16 + bb) * 8) + j0] = pk;
  }
  __syncthreads();

  const int wvp = tid >> 6, lane = tid & 63, ln16 = lane & 15;
  const int qp = lane >> 4;

  short8 aF[12];
#pragma unroll
  for (int kk = 0; kk < 12; ++kk) aF[kk] = *(const short8*)&xF[(kk * 64 + lane) * 8];

  // this lane's C-rows are batch rows mt*16 + qp*4 + r  ->  rnn wg = mt*4+qp
  unsigned* slab = pre2 + (size_t)((mt * 4 + qp) * SEQL + t) * 1536;

#pragma unroll
  for (int ig = 0; ig < 3; ++ig) {
    const int ngrp = wvp * 3 + ig;                 // 0..11 -> 64-col group
    const float sc = (ngrp >= 8) ? PL2E2 : NL2E;
    floatx4 acc[4];
#pragma unroll
    for (int nt = 0; nt < 4; ++nt) {
      float bv = bias[ngrp * 64 + nt * 16 + ln16] * sc;
#pragma unroll
      for (int r = 0; r < 4; ++r) acc[nt][r] = bv;
    }
#pragma unroll
    for (int kk = 0; kk < 12; ++kk) {
#pragma unroll
      for (int nt = 0; nt < 4; ++nt) {
        int n = ngrp * 64 + nt * 16 + ln16;
        short8 w = *(const short8*)(WcB + (((size_t)(n * 12 + kk) * 4 + qp) * 8));
        acc[nt] = __builtin_amdgcn_mfma_f32_16x16x32_bf16(aF[kk], w, acc[nt], 0, 0, 0);
      }
    }
    const int g = ngrp >> 2;                       // gate 0:r 1:u 2:h
#pragma unroll
    for (int p = 0; p < 2; ++p) {                  // nt_p pair (2p, 2p+1)
      int wv = (ngrp & 3) * 2 + p;                 // consuming rnn wave
#pragma unroll
      for (int r = 0; r < 4; ++r) {
        unsigned lo = (unsigned)(unsigned short)f2bf(acc[2 * p][r]);
        unsigned hi = (unsigned)(unsigned short)f2bf(acc[2 * p + 1][r]);
        slab[g * 512 + wv * 64 + r * 16 + ln16] = lo | (hi << 16);
      }
    }
  }
}

// ---------------------------------------------------------------------------
// Kernel C: persistent recurrence. 32 WGs x 512 threads; 4 batch rows per WG.
// h/rh stored compactly (4 x 256 bf16, stride 272); A-frag built as
// A[m][k] = h[m&3][k] (4-way broadcast LDS reads, 256B unique per read).
// C-frag then has reg r == batch row r for every lane; a 3-cndmask select
// (by q) gives all 64 lanes exactly 2 unique values per gate.
// ---------------------------------------------------------------------------
__global__ __launch_bounds__(512, 2) void rnn_kernel(const unsigned* __restrict__ pre2,
                                                     const short* __restrict__ WhB,
                                                     float* __restrict__ out) {
  __shared__ __align__(16) short hFc[4 * HSTRIDE];   // h,  rows 0..3 compact
  __shared__ __align__(16) short rFc[4 * HSTRIDE];   // r*h

  const int tid = threadIdx.x;
  const int wv = tid >> 6, lane = tid & 63, ln16 = lane & 15, q = lane >> 4;
  const int row4 = lane & 3;            // A-frag source row (m & 3)
  const int wg = blockIdx.x;

  // persistent weight fragments: this wave's 32 cols of each gate
  short8 wR[2][8], wU[2][8], wH[2][8];
#pragma unroll
  for (int nt = 0; nt < 2; ++nt) {
    int nr = wv * 32 + nt * 16 + ln16;
#pragma unroll
    for (int kk = 0; kk < 8; ++kk) {
      wR[nt][kk] = *(const short8*)(WhB + (((size_t)(nr * 8 + kk) * 4 + q) * 8));
      wU[nt][kk] = *(const short8*)(WhB + (((size_t)((256 + nr) * 8 + kk) * 4 + q) * 8));
      wH[nt][kk] = *(const short8*)(WhB + (((size_t)((512 + nr) * 8 + kk) * 4 + q) * 8));
    }
  }
  for (int i = tid; i < 4 * HSTRIDE; i += 512) { hFc[i] = 0; rFc[i] = 0; }

  const floatx4 z4 = {0.f, 0.f, 0.f, 0.f};
  float hq[2] = {0.f, 0.f};             // h(row=q, col = wv*32 + nt*16 + ln16)

  const unsigned* slab0 = pre2 + (size_t)wg * SEQL * 1536;
  unsigned cur0 = slab0[0 * 512 + tid];
  unsigned cur1 = slab0[1 * 512 + tid];
  unsigned cur2 = slab0[2 * 512 + tid];

  float* outBase = out + ((size_t)(wg * 4 + q) * SEQL) * UNITS + wv * 32 + ln16;
  const int aoff = row4 * HSTRIDE + q * 8;       // + kk*32 per step
  const int woff = q * HSTRIDE + wv * 32 + ln16; // + nt*16

  __syncthreads();

  for (int t = 0; t < SEQL; ++t) {
    const unsigned* nslab = slab0 + (size_t)(t < SEQL - 1 ? t + 1 : t) * 1536;
    unsigned nxt0 = nslab[0 * 512 + tid];
    unsigned nxt1 = nslab[1 * 512 + tid];
    unsigned nxt2 = nslab[2 * 512 + tid];

    // ---- phase A: r,u pre-acts ----
    floatx4 accR[2], accU[2];
    {
      const short8 a0 = *(const short8*)&hFc[aoff];
      accR[0] = __builtin_amdgcn_mfma_f32_16x16x32_bf16(a0, wR[0][0], z4, 0, 0, 0);
      accR[1] = __builtin_amdgcn_mfma_f32_16x16x32_bf16(a0, wR[1][0], z4, 0, 0, 0);
      accU[0] = __builtin_amdgcn_mfma_f32_16x16x32_bf16(a0, wU[0][0], z4, 0, 0, 0);
      accU[1] = __builtin_amdgcn_mfma_f32_16x16x32_bf16(a0, wU[1][0], z4, 0, 0, 0);
    }
#pragma unroll
    for (int kk = 1; kk < 8; ++kk) {
      const short8 a = *(const short8*)&hFc[aoff + kk * 32];
      accR[0] = __builtin_amdgcn_mfma_f32_16x16x32_bf16(a, wR[0][kk], accR[0], 0, 0, 0);
      accR[1] = __builtin_amdgcn_mfma_f32_16x16x32_bf16(a, wR[1][kk], accR[1], 0, 0, 0);
      accU[0] = __builtin_amdgcn_mfma_f32_16x16x32_bf16(a, wU[0][kk], accU[0], 0, 0, 0);
      accU[1] = __builtin_amdgcn_mfma_f32_16x16x32_bf16(a, wU[1][kk], accU[1], 0, 0, 0);
    }
    float uq[2];
#pragma unroll
    for (int nt = 0; nt < 2; ++nt) {
      float vR = (q == 0) ? accR[nt][0] : (q == 1) ? accR[nt][1]
               : (q == 2) ? accR[nt][2] : accR[nt][3];
      float vU = (q == 0) ? accU[nt][0] : (q == 1) ? accU[nt][1]
               : (q == 2) ? accU[nt][2] : accU[nt][3];
      float pR = bf2f((unsigned short)(nt ? (cur0 >> 16) : (cur0 & 0xffff)));
      float pU = bf2f((unsigned short)(nt ? (cur1 >> 16) : (cur1 & 0xffff)));
      float rg = frcp(1.f + fexp2(vR + pR));
      uq[nt]   = frcp(1.f + fexp2(vU + pU));
      rFc[woff + nt * 16] = f2bf(rg * hq[nt]);
    }
    __syncthreads();

    // ---- phase B: cand, h update ----
    floatx4 accH[2];
    {
      const short8 a0 = *(const short8*)&rFc[aoff];
      accH[0] = __builtin_amdgcn_mfma_f32_16x16x32_bf16(a0, wH[0][0], z4, 0, 0, 0);
      accH[1] = __builtin_amdgcn_mfma_f32_16x16x32_bf16(a0, wH[1][0], z4, 0, 0, 0);
    }
#pragma unroll
    for (int kk = 1; kk < 8; ++kk) {
      const short8 a = *(const short8*)&rFc[aoff + kk * 32];
      accH[0] = __builtin_amdgcn_mfma_f32_16x16x32_bf16(a, wH[0][kk], accH[0], 0, 0, 0);
      accH[1] = __builtin_amdgcn_mfma_f32_16x16x32_bf16(a, wH[1][kk], accH[1], 0, 0, 0);
    }
#pragma unroll
    for (int nt = 0; nt < 2; ++nt) {
      float vH = (q == 0) ? accH[nt][0] : (q == 1) ? accH[nt][1]
               : (q == 2) ? accH[nt][2] : accH[nt][3];
      float pH = bf2f((unsigned short)(nt ? (cur2 >> 16) : (cur2 & 0xffff)));
      float cand = 1.f - 2.f * frcp(1.f + fexp2(vH + pH));   // tanh (scale folded)
      float hnew = uq[nt] * (hq[nt] - cand) + cand;
      hq[nt] = hnew;
      hFc[woff + nt * 16] = f2bf(hnew);
      outBase[(size_t)t * UNITS + nt * 16] = hnew;
    }
    cur0 = nxt0; cur1 = nxt1; cur2 = nxt2;
    __syncthreads();
  }
}

extern "C" void kernel_launch(void* const* d_in, const int* in_sizes, int n_in,
                              void* d_out, int out_size, void* d_ws, size_t ws_size,
                              hipStream_t stream) {
  const float* x    = (const float*)d_in[0];
  const float* iw   = (const float*)d_in[1];
  const float* hw   = (const float*)d_in[2];
  const float* bias = (const float*)d_in[3];
  // d_in[4] (constant) is [I;0] — folded analytically, unused.
  float* out = (float*)d_out;

  unsigned* pre2 = (unsigned*)d_ws;                    // 32*1024*1536 dwords = 192 MB
  const size_t preDwords = (size_t)32 * SEQL * 1536;
  short* WcB = (short*)(pre2 + preDwords);             // 384*768 bf16
  short* WhB = WcB + (size_t)384 * G3;                 // 256*768 bf16

  prep_kernel<<<1920, 256, 0, stream>>>(iw, hw, WcB, WhB);
  proj_kernel<<<8192, 256, 0, stream>>>(x, WcB, bias, pre2);
  rnn_kernel<<<32, 512, 0, stream>>>(pre2, WhB, out);
}